// Round 3
// baseline (49.671 us; speedup 1.0000x reference)
//
#include <hip/hip_runtime.h>

#define N 512
#define D 128
#define TS 64
// 1000 * log2(e): sigmoid(x/K) = 1/(1+exp(-x*1000)) = 1/(1+exp2(-x*SCALE))
#define RS_SCALE 1442.6950408889634f

static __device__ __forceinline__ float rcp_fast(float x) {
    return __builtin_amdgcn_rcpf(x);
}
static __device__ __forceinline__ float exp2_fast(float x) {
    return __builtin_amdgcn_exp2f(x);
}

// ---------------- K0: per-row inverse norms ----------------
__global__ __launch_bounds__(64) void map_norm_kernel(
    const float* __restrict__ x, float* __restrict__ invn)
{
    int r = blockIdx.x * 64 + threadIdx.x;
    const float4* p = (const float4*)(x + r * D);
    float ss = 0.f;
#pragma unroll
    for (int d = 0; d < D / 4; ++d) {
        float4 v = p[d];
        ss = fmaf(v.x, v.x, ss);
        ss = fmaf(v.y, v.y, ss);
        ss = fmaf(v.z, v.z, ss);
        ss = fmaf(v.w, v.w, ss);
    }
    invn[r] = 1.0f / fmaxf(sqrtf(ss), 1e-8f);
}

// ---------------- K1: scaled cosine-sim matrix (64x64-tiled GEMM) ----------
// rs[i*N+c] = dot(xn_i, xn_c) * RS_SCALE
__global__ __launch_bounds__(256) void map_sim_kernel(
    const float* __restrict__ x, const float* __restrict__ invn,
    float* __restrict__ rs)
{
    const int bi = blockIdx.x;
    const int bj = blockIdx.y;
    const int t = threadIdx.x;

    __shared__ float As[TS * D];
    __shared__ float Bs[TS * D];

    // load 64 rows x 128 cols per tile; XOR-swizzle float4 granules so
    // fragment reads (rows stride 4) spread across banks
    for (int r = 0; r < 8; ++r) {
        int ch = t + 256 * r;           // [0,2048)
        int row = ch >> 5, c4 = ch & 31;
        int sw = (c4 ^ (row & 31)) << 2;
        float sa = invn[bi * TS + row];
        float4 va = *(const float4*)(x + (bi * TS + row) * D + c4 * 4);
        *(float4*)(As + row * D + sw) =
            make_float4(va.x * sa, va.y * sa, va.z * sa, va.w * sa);
        float sb = invn[bj * TS + row];
        float4 vb = *(const float4*)(x + (bj * TS + row) * D + c4 * 4);
        *(float4*)(Bs + row * D + sw) =
            make_float4(vb.x * sb, vb.y * sb, vb.z * sb, vb.w * sb);
    }
    __syncthreads();

    const int tx = t & 15, ty = t >> 4;
    float acc[4][4] = {};
#pragma unroll 4
    for (int k4 = 0; k4 < D / 4; ++k4) {
        float4 a[4], b[4];
#pragma unroll
        for (int r = 0; r < 4; ++r) {
            int ra = ty * 4 + r;
            a[r] = *(const float4*)(As + ra * D + ((k4 ^ (ra & 31)) << 2));
            int rb = tx * 4 + r;
            b[r] = *(const float4*)(Bs + rb * D + ((k4 ^ (rb & 31)) << 2));
        }
#pragma unroll
        for (int r = 0; r < 4; ++r)
#pragma unroll
            for (int s = 0; s < 4; ++s) {
                acc[r][s] = fmaf(a[r].x, b[s].x, acc[r][s]);
                acc[r][s] = fmaf(a[r].y, b[s].y, acc[r][s]);
                acc[r][s] = fmaf(a[r].z, b[s].z, acc[r][s]);
                acc[r][s] = fmaf(a[r].w, b[s].w, acc[r][s]);
            }
    }
#pragma unroll
    for (int r = 0; r < 4; ++r) {
        int gr = bi * TS + ty * 4 + r;
        float4 o = make_float4(acc[r][0] * RS_SCALE, acc[r][1] * RS_SCALE,
                               acc[r][2] * RS_SCALE, acc[r][3] * RS_SCALE);
        *(float4*)(rs + gr * N + bj * TS + tx * 4) = o;
    }
}

// ---------------- K3: O(n^2)-per-block AP core ----------------
// block b: row i = b>>1, j-half jh = b&1. 512 threads: jl = t&255 (j index
// within half), lh = t>>8 (l-half). Each thread: 256 l for one j.
__global__ __launch_bounds__(512) void map_main_kernel(
    const float* __restrict__ rs, const int* __restrict__ tgt,
    float2* __restrict__ av)
{
    const int b = blockIdx.x;
    const int i = b >> 1;
    const int jh = b & 1;
    const int t = threadIdx.x;

    __shared__ float2 rg[N];   // [l] = {scaled sim, gt}; slot 511 = pad
    __shared__ float2 pd[256]; // lh=1 partials
    __shared__ float red[16];

    const int ti = tgt[i];
    {
        const int c = t;
        if (c < N) {
            float rsv = rs[i * N + c];
            if (c != i) {
                int l = c - (c > i);
                rg[l] = make_float2(rsv, (tgt[c] == ti) ? 1.f : 0.f);
            } else {
                rg[N - 1] = make_float2(-1e30f, 0.f);  // pad slot
            }
        }
    }
    __syncthreads();

    const int jl = t & 255;
    const int lh = t >> 8;
    const int j = jh * 256 + jl;
    const float rj = rg[j].x;
    const float gtj = rg[j].y;

    const float4* rg4 = (const float4*)rg;  // 2 l per read
    float dsum = 0.f, gsum = 0.f;
#pragma unroll 8
    for (int q = 0; q < 128; ++q) {
        float4 p = rg4[lh * 128 + q];  // broadcast within wave
        // indicator = sigmoid((r_l - r_j)/K) = 1/(1+exp2(rs_j - rs_l))
        float e1 = exp2_fast(rj - p.x);
        float e2 = exp2_fast(rj - p.z);
        float s1 = rcp_fast(1.f + e1);
        float s2 = rcp_fast(1.f + e2);
        dsum += s1 + s2;
        gsum = fmaf(p.y, s1, gsum);
        gsum = fmaf(p.w, s2, gsum);
    }

    if (lh == 1) pd[jl] = make_float2(dsum, gsum);
    __syncthreads();

    float ap = 0.f, np = 0.f;
    if (lh == 0) {
        float2 o = pd[jl];
        float dt = dsum + o.x + 0.5f;
        float gt_ = gsum + o.y;
        float prec = gt_ * rcp_fast(dt);
        ap = gtj * prec;
        np = gtj;
    }

#pragma unroll
    for (int off = 32; off; off >>= 1) {
        ap += __shfl_down(ap, off);
        np += __shfl_down(np, off);
    }
    int w = t >> 6;
    if ((t & 63) == 0) { red[w * 2] = ap; red[w * 2 + 1] = np; }
    __syncthreads();
    if (t == 0) {
        float A = 0.f, P = 0.f;
#pragma unroll
        for (int k = 0; k < 8; ++k) { A += red[2 * k]; P += red[2 * k + 1]; }
        av[b] = make_float2(A, P);  // partial (half the j's of row i)
    }
}

// ---------------- K4: final scalar ----------------
__global__ __launch_bounds__(256) void map_final_kernel(
    const float2* __restrict__ av, float* __restrict__ out)
{
    int t = threadIdx.x;
    float a = 0.f, v = 0.f;
#pragma unroll
    for (int k = 0; k < 2; ++k) {
        int r = t + k * 256;  // row index
        float2 p0 = av[2 * r], p1 = av[2 * r + 1];
        float A = p0.x + p1.x;
        float P = p0.y + p1.y;
        a += (P > 0.f) ? (A / P) : 0.f;
        v += (P > 0.f) ? 1.f : 0.f;
    }
#pragma unroll
    for (int off = 32; off; off >>= 1) {
        a += __shfl_down(a, off);
        v += __shfl_down(v, off);
    }
    __shared__ float red[8];
    int w = t >> 6;
    if ((t & 63) == 0) { red[w * 2] = a; red[w * 2 + 1] = v; }
    __syncthreads();
    if (t == 0) {
        float A = red[0] + red[2] + red[4] + red[6];
        float V = red[1] + red[3] + red[5] + red[7];
        out[0] = 1.0f - A / V;
    }
}

extern "C" void kernel_launch(void* const* d_in, const int* in_sizes, int n_in,
                              void* d_out, int out_size, void* d_ws, size_t ws_size,
                              hipStream_t stream) {
    const float* x = (const float*)d_in[0];
    const int* tgt = (const int*)d_in[1];
    float* out = (float*)d_out;

    float* rs = (float*)d_ws;                            // N*N floats = 1 MB
    float* invn = (float*)((char*)d_ws + N * N * 4);     // 512 floats
    float2* av = (float2*)((char*)d_ws + N * N * 4 + 4096);  // 1024 float2

    map_norm_kernel<<<N / 64, 64, 0, stream>>>(x, invn);
    map_sim_kernel<<<dim3(N / TS, N / TS), 256, 0, stream>>>(x, invn, rs);
    map_main_kernel<<<2 * N, 512, 0, stream>>>(rs, tgt, av);
    map_final_kernel<<<1, 256, 0, stream>>>(av, out);
}

// Round 4
// 40.313 us; speedup vs baseline: 1.2321x; 1.2321x over previous
//
#include <hip/hip_runtime.h>

#define N 512
#define D 128
#define TS 64
// 1000 * log2(e): sigmoid(x/K) = 1/(1+exp(-x*1000)) = 1/(1+exp2(-x*SCALE))
#define RS_SCALE 1442.6950408889634f
// |scaled diff| > WINDOW_T => sigmoid is 0/1 to within 2^-18
#define WINDOW_T 18.0f

static __device__ __forceinline__ float rcp_fast(float x) {
    return __builtin_amdgcn_rcpf(x);
}
static __device__ __forceinline__ float exp2_fast(float x) {
    return __builtin_amdgcn_exp2f(x);
}

// ---------------- K0: per-row inverse norms ----------------
__global__ __launch_bounds__(64) void map_norm_kernel(
    const float* __restrict__ x, float* __restrict__ invn)
{
    int r = blockIdx.x * 64 + threadIdx.x;
    const float4* p = (const float4*)(x + r * D);
    float ss = 0.f;
#pragma unroll
    for (int d = 0; d < D / 4; ++d) {
        float4 v = p[d];
        ss = fmaf(v.x, v.x, ss);
        ss = fmaf(v.y, v.y, ss);
        ss = fmaf(v.z, v.z, ss);
        ss = fmaf(v.w, v.w, ss);
    }
    invn[r] = 1.0f / fmaxf(sqrtf(ss), 1e-8f);
}

// ---------------- K1: scaled cosine-sim matrix (64x64-tiled GEMM) ----------
__global__ __launch_bounds__(256) void map_sim_kernel(
    const float* __restrict__ x, const float* __restrict__ invn,
    float* __restrict__ rs)
{
    const int bi = blockIdx.x;
    const int bj = blockIdx.y;
    const int t = threadIdx.x;

    __shared__ float As[TS * D];
    __shared__ float Bs[TS * D];

    for (int r = 0; r < 8; ++r) {
        int ch = t + 256 * r;           // [0,2048)
        int row = ch >> 5, c4 = ch & 31;
        int sw = (c4 ^ (row & 31)) << 2;
        float sa = invn[bi * TS + row];
        float4 va = *(const float4*)(x + (bi * TS + row) * D + c4 * 4);
        *(float4*)(As + row * D + sw) =
            make_float4(va.x * sa, va.y * sa, va.z * sa, va.w * sa);
        float sb = invn[bj * TS + row];
        float4 vb = *(const float4*)(x + (bj * TS + row) * D + c4 * 4);
        *(float4*)(Bs + row * D + sw) =
            make_float4(vb.x * sb, vb.y * sb, vb.z * sb, vb.w * sb);
    }
    __syncthreads();

    const int tx = t & 15, ty = t >> 4;
    float acc[4][4] = {};
#pragma unroll 4
    for (int k4 = 0; k4 < D / 4; ++k4) {
        float4 a[4], b[4];
#pragma unroll
        for (int r = 0; r < 4; ++r) {
            int ra = ty * 4 + r;
            a[r] = *(const float4*)(As + ra * D + ((k4 ^ (ra & 31)) << 2));
            int rb = tx * 4 + r;
            b[r] = *(const float4*)(Bs + rb * D + ((k4 ^ (rb & 31)) << 2));
        }
#pragma unroll
        for (int r = 0; r < 4; ++r)
#pragma unroll
            for (int s = 0; s < 4; ++s) {
                acc[r][s] = fmaf(a[r].x, b[s].x, acc[r][s]);
                acc[r][s] = fmaf(a[r].y, b[s].y, acc[r][s]);
                acc[r][s] = fmaf(a[r].z, b[s].z, acc[r][s]);
                acc[r][s] = fmaf(a[r].w, b[s].w, acc[r][s]);
            }
    }
#pragma unroll
    for (int r = 0; r < 4; ++r) {
        int gr = bi * TS + ty * 4 + r;
        float4 o = make_float4(acc[r][0] * RS_SCALE, acc[r][1] * RS_SCALE,
                               acc[r][2] * RS_SCALE, acc[r][3] * RS_SCALE);
        *(float4*)(rs + gr * N + bj * TS + tx * 4) = o;
    }
}

// ---------------- K2: sort + windowed-sigmoid AP ----------------
// one block per row i, 512 threads. Sort the row's scaled sims (self-slot
// doubles as a -1e30 pad that sorts to the bottom and contributes 0 to all
// sums). For each sorted position p: elements above p's +-WINDOW_T window
// contribute exactly 1 (suffix count / gt suffix sum); the ~58-wide window
// gets exact sigmoids; below-window contributes < 2^-18 each (dropped).
__global__ __launch_bounds__(512) void map_ap_sort_kernel(
    const float* __restrict__ rs, const int* __restrict__ tgt,
    float2* __restrict__ av)
{
    const int i = blockIdx.x;
    const int t = threadIdx.x;

    __shared__ float keys[N];
    __shared__ float gts[N];
    __shared__ float gtsuf[N + 1];
    __shared__ float red[16];

    const int ti = tgt[i];
    keys[t] = (t == i) ? -1e30f : rs[i * N + t];
    gts[t] = (t != i && tgt[t] == ti) ? 1.f : 0.f;

    // bitonic sort ascending (keys, gts payload)
    for (int k = 2; k <= N; k <<= 1) {
        for (int jj = k >> 1; jj > 0; jj >>= 1) {
            __syncthreads();
            int ixj = t ^ jj;
            if (ixj > t) {
                float a = keys[t], b2 = keys[ixj];
                bool up = ((t & k) == 0);
                if (up ? (a > b2) : (a < b2)) {
                    keys[t] = b2; keys[ixj] = a;
                    float g = gts[t]; gts[t] = gts[ixj]; gts[ixj] = g;
                }
            }
        }
    }
    __syncthreads();

    // suffix sum of gts (Hillis-Steele, in place)
    gtsuf[t] = gts[t];
    if (t == 0) gtsuf[N] = 0.f;
    __syncthreads();
    for (int off = 1; off < N; off <<= 1) {
        float add = (t + off < N) ? gtsuf[t + off] : 0.f;
        __syncthreads();
        gtsuf[t] += add;
        __syncthreads();
    }

    const float rj = keys[t];
    const float gtj = gts[t];

    // u = first index with key > rj + T  (elements >= u contribute 1)
    int lo = 0, hi = N;
    const float upthr = rj + WINDOW_T;
    while (lo < hi) {
        int mid = (lo + hi) >> 1;
        if (keys[mid] > upthr) hi = mid; else lo = mid + 1;
    }
    const int u = lo;
    // b = first index with key >= rj - T  (elements < b contribute ~0)
    lo = 0; hi = N;
    const float lothr = rj - WINDOW_T;
    while (lo < hi) {
        int mid = (lo + hi) >> 1;
        if (keys[mid] >= lothr) hi = mid; else lo = mid + 1;
    }
    const int b = lo;

    float dsum = (float)(N - u);
    float gsum = gtsuf[u];
    for (int q = b; q < u; ++q) {
        // sigmoid((r_l - r_j)/K) = 1/(1+exp2(rs_j - rs_l)); q==p gives 0.5
        float s = rcp_fast(1.f + exp2_fast(rj - keys[q]));
        dsum += s;
        gsum = fmaf(gts[q], s, gsum);
    }

    float prec = gsum * rcp_fast(dsum + 0.5f);
    float ap = gtj * prec;   // pad thread: gtj = 0
    float np = gtj;

    // block reduction (8 waves)
#pragma unroll
    for (int off = 32; off; off >>= 1) {
        ap += __shfl_down(ap, off);
        np += __shfl_down(np, off);
    }
    int w = t >> 6;
    if ((t & 63) == 0) { red[w * 2] = ap; red[w * 2 + 1] = np; }
    __syncthreads();
    if (t == 0) {
        float A = 0.f, P = 0.f;
#pragma unroll
        for (int k = 0; k < 8; ++k) { A += red[2 * k]; P += red[2 * k + 1]; }
        float apn = (P > 0.f) ? (A * rcp_fast(P)) : 0.f;
        av[i] = make_float2(apn, (P > 0.f) ? 1.f : 0.f);
    }
}

// ---------------- K3: final scalar ----------------
__global__ __launch_bounds__(256) void map_final_kernel(
    const float2* __restrict__ av, float* __restrict__ out)
{
    int t = threadIdx.x;
    float a = 0.f, v = 0.f;
    for (int k = t; k < N; k += 256) {
        float2 p = av[k];
        a += p.x;
        v += p.y;
    }
#pragma unroll
    for (int off = 32; off; off >>= 1) {
        a += __shfl_down(a, off);
        v += __shfl_down(v, off);
    }
    __shared__ float red[8];
    int w = t >> 6;
    if ((t & 63) == 0) { red[w * 2] = a; red[w * 2 + 1] = v; }
    __syncthreads();
    if (t == 0) {
        float A = red[0] + red[2] + red[4] + red[6];
        float V = red[1] + red[3] + red[5] + red[7];
        out[0] = 1.0f - A / V;
    }
}

extern "C" void kernel_launch(void* const* d_in, const int* in_sizes, int n_in,
                              void* d_out, int out_size, void* d_ws, size_t ws_size,
                              hipStream_t stream) {
    const float* x = (const float*)d_in[0];
    const int* tgt = (const int*)d_in[1];
    float* out = (float*)d_out;

    float* rs = (float*)d_ws;                                // N*N floats = 1 MB
    float* invn = (float*)((char*)d_ws + N * N * 4);         // 512 floats
    float2* av = (float2*)((char*)d_ws + N * N * 4 + 4096);  // 512 float2

    map_norm_kernel<<<N / 64, 64, 0, stream>>>(x, invn);
    map_sim_kernel<<<dim3(N / TS, N / TS), 256, 0, stream>>>(x, invn, rs);
    map_ap_sort_kernel<<<N, 512, 0, stream>>>(rs, tgt, av);
    map_final_kernel<<<1, 256, 0, stream>>>(av, out);
}

// Round 5
// 30.346 us; speedup vs baseline: 1.6368x; 1.3285x over previous
//
#include <hip/hip_runtime.h>

#define N 512
#define D 128
#define TS 64
// 1000 * log2(e): sigmoid(x/K) = 1/(1+exp(-x*1000)) = 1/(1+exp2(-x*SCALE))
#define RS_SCALE 1442.6950408889634f
// bucket width == far-threshold: bucket distance >=2 guarantees diff > 18
#define W_INV (1.0f / 18.0f)
#define B_OFF 1530.0f
#define NB 172
#define SCAN_N 256

static __device__ __forceinline__ float rcp_fast(float x) {
    return __builtin_amdgcn_rcpf(x);
}
static __device__ __forceinline__ float exp2_fast(float x) {
    return __builtin_amdgcn_exp2f(x);
}

// ---------------- K0: per-row inverse norms ----------------
__global__ __launch_bounds__(64) void map_norm_kernel(
    const float* __restrict__ x, float* __restrict__ invn)
{
    int r = blockIdx.x * 64 + threadIdx.x;
    const float4* p = (const float4*)(x + r * D);
    float ss = 0.f;
#pragma unroll
    for (int d = 0; d < D / 4; ++d) {
        float4 v = p[d];
        ss = fmaf(v.x, v.x, ss);
        ss = fmaf(v.y, v.y, ss);
        ss = fmaf(v.z, v.z, ss);
        ss = fmaf(v.w, v.w, ss);
    }
    invn[r] = 1.0f / fmaxf(sqrtf(ss), 1e-8f);
}

// ---------------- K1: scaled cosine-sim matrix (64x64-tiled GEMM) ----------
__global__ __launch_bounds__(256) void map_sim_kernel(
    const float* __restrict__ x, const float* __restrict__ invn,
    float* __restrict__ rs)
{
    const int bi = blockIdx.x;
    const int bj = blockIdx.y;
    const int t = threadIdx.x;

    __shared__ float As[TS * D];
    __shared__ float Bs[TS * D];

    for (int r = 0; r < 8; ++r) {
        int ch = t + 256 * r;           // [0,2048)
        int row = ch >> 5, c4 = ch & 31;
        int sw = (c4 ^ (row & 31)) << 2;
        float sa = invn[bi * TS + row];
        float4 va = *(const float4*)(x + (bi * TS + row) * D + c4 * 4);
        *(float4*)(As + row * D + sw) =
            make_float4(va.x * sa, va.y * sa, va.z * sa, va.w * sa);
        float sb = invn[bj * TS + row];
        float4 vb = *(const float4*)(x + (bj * TS + row) * D + c4 * 4);
        *(float4*)(Bs + row * D + sw) =
            make_float4(vb.x * sb, vb.y * sb, vb.z * sb, vb.w * sb);
    }
    __syncthreads();

    const int tx = t & 15, ty = t >> 4;
    float acc[4][4] = {};
#pragma unroll 4
    for (int k4 = 0; k4 < D / 4; ++k4) {
        float4 a[4], b[4];
#pragma unroll
        for (int r = 0; r < 4; ++r) {
            int ra = ty * 4 + r;
            a[r] = *(const float4*)(As + ra * D + ((k4 ^ (ra & 31)) << 2));
            int rb = tx * 4 + r;
            b[r] = *(const float4*)(Bs + rb * D + ((k4 ^ (rb & 31)) << 2));
        }
#pragma unroll
        for (int r = 0; r < 4; ++r)
#pragma unroll
            for (int s = 0; s < 4; ++s) {
                acc[r][s] = fmaf(a[r].x, b[s].x, acc[r][s]);
                acc[r][s] = fmaf(a[r].y, b[s].y, acc[r][s]);
                acc[r][s] = fmaf(a[r].z, b[s].z, acc[r][s]);
                acc[r][s] = fmaf(a[r].w, b[s].w, acc[r][s]);
            }
    }
#pragma unroll
    for (int r = 0; r < 4; ++r) {
        int gr = bi * TS + ty * 4 + r;
        float4 o = make_float4(acc[r][0] * RS_SCALE, acc[r][1] * RS_SCALE,
                               acc[r][2] * RS_SCALE, acc[r][3] * RS_SCALE);
        *(float4*)(rs + gr * N + bj * TS + tx * 4) = o;
    }
}

// ---------------- K2: counting-sort + windowed-sigmoid AP ----------------
// one block per row i, 512 threads. Bucket counting sort (width 18 = window
// threshold). Buckets >= q+2: diff > 18 -> contribute exactly 1 (suffix via
// scanned histogram). Buckets [q-1, q+1]: exact sigmoid. Buckets <= q-2:
// < 2^-18 each, dropped. Self-slot = -1e30 pad (bucket 0, gt 0 -> inert).
__global__ __launch_bounds__(512) void map_ap_bucket_kernel(
    const float* __restrict__ rs, const int* __restrict__ tgt,
    float2* __restrict__ av)
{
    const int i = blockIdx.x;
    const int t = threadIdx.x;

    __shared__ int hist[SCAN_N];   // packed (count<<10)|gtcount; then incl scan
    __shared__ int offs[NB];
    __shared__ float skey[N];
    __shared__ float sgt[N];
    __shared__ float red[16];

    // phase 0: zero histograms, load row element, bucket it
    if (t < SCAN_N) hist[t] = 0;
    if (t < NB) offs[t] = 0;
    const int ti = tgt[i];
    const bool self = (t == i);
    const float val = self ? -1e30f : rs[i * N + t];
    const float gt = (!self && tgt[t] == ti) ? 1.f : 0.f;
    int q = (int)((val + B_OFF) * W_INV);
    q = max(0, min(NB - 1, q));
    __syncthreads();
    atomicAdd(&hist[q], (1 << 10) | (int)gt);
    __syncthreads();

    // phase 1: inclusive scan of hist[0..255] (packed fields scan together)
    for (int off = 1; off < SCAN_N; off <<= 1) {
        int v = 0;
        if (t < SCAN_N) {
            v = hist[t];
            if (t >= off) v += hist[t - off];
        }
        __syncthreads();
        if (t < SCAN_N) hist[t] = v;
        __syncthreads();
    }

    // phase 2: scatter into bucket-sorted arrays
    {
        int base = (q > 0) ? (hist[q - 1] >> 10) : 0;
        int pos = base + atomicAdd(&offs[q], 1);
        skey[pos] = val;
        sgt[pos] = gt;
    }
    __syncthreads();

    // phase 3: j = sorted position t
    const float rj = skey[t];
    const float gtj = sgt[t];
    int qj = (int)((rj + B_OFF) * W_INV);
    qj = max(0, min(NB - 1, qj));
    const int lo = (qj > 1) ? (hist[qj - 2] >> 10) : 0;    // start of bucket qj-1
    const int e = min(qj + 2, NB);
    const int hi = hist[e - 1] >> 10;                      // end of bucket qj+1
    const int totpk = hist[NB - 1];

    float dsum = (float)(N - hi);                          // far: all 1's
    float gsum = (float)((totpk & 1023) - (hist[e - 1] & 1023));
    for (int idx = lo; idx < hi; ++idx) {
        // sigmoid((r_l - r_j)/K) = 1/(1+exp2(rs_j - rs_l)); idx==t gives 0.5
        float s = rcp_fast(1.f + exp2_fast(rj - skey[idx]));
        dsum += s;
        gsum = fmaf(sgt[idx], s, gsum);
    }

    float prec = gsum * rcp_fast(dsum + 0.5f);
    float ap = gtj * prec;   // pad thread: gtj = 0
    float np = gtj;

    // block reduction (8 waves)
#pragma unroll
    for (int off = 32; off; off >>= 1) {
        ap += __shfl_down(ap, off);
        np += __shfl_down(np, off);
    }
    int w = t >> 6;
    if ((t & 63) == 0) { red[w * 2] = ap; red[w * 2 + 1] = np; }
    __syncthreads();
    if (t == 0) {
        float A = 0.f, P = 0.f;
#pragma unroll
        for (int k = 0; k < 8; ++k) { A += red[2 * k]; P += red[2 * k + 1]; }
        float apn = (P > 0.f) ? (A * rcp_fast(P)) : 0.f;
        av[i] = make_float2(apn, (P > 0.f) ? 1.f : 0.f);
    }
}

// ---------------- K3: final scalar ----------------
__global__ __launch_bounds__(256) void map_final_kernel(
    const float2* __restrict__ av, float* __restrict__ out)
{
    int t = threadIdx.x;
    float a = 0.f, v = 0.f;
    for (int k = t; k < N; k += 256) {
        float2 p = av[k];
        a += p.x;
        v += p.y;
    }
#pragma unroll
    for (int off = 32; off; off >>= 1) {
        a += __shfl_down(a, off);
        v += __shfl_down(v, off);
    }
    __shared__ float red[8];
    int w = t >> 6;
    if ((t & 63) == 0) { red[w * 2] = a; red[w * 2 + 1] = v; }
    __syncthreads();
    if (t == 0) {
        float A = red[0] + red[2] + red[4] + red[6];
        float V = red[1] + red[3] + red[5] + red[7];
        out[0] = 1.0f - A / V;
    }
}

extern "C" void kernel_launch(void* const* d_in, const int* in_sizes, int n_in,
                              void* d_out, int out_size, void* d_ws, size_t ws_size,
                              hipStream_t stream) {
    const float* x = (const float*)d_in[0];
    const int* tgt = (const int*)d_in[1];
    float* out = (float*)d_out;

    float* rs = (float*)d_ws;                                // N*N floats = 1 MB
    float* invn = (float*)((char*)d_ws + N * N * 4);         // 512 floats
    float2* av = (float2*)((char*)d_ws + N * N * 4 + 4096);  // 512 float2

    map_norm_kernel<<<N / 64, 64, 0, stream>>>(x, invn);
    map_sim_kernel<<<dim3(N / TS, N / TS), 256, 0, stream>>>(x, invn, rs);
    map_ap_bucket_kernel<<<N, 512, 0, stream>>>(rs, tgt, av);
    map_final_kernel<<<1, 256, 0, stream>>>(av, out);
}

// Round 6
// 29.863 us; speedup vs baseline: 1.6633x; 1.0162x over previous
//
#include <hip/hip_runtime.h>

#define N 512
#define D 128
#define TS 32
// 1000 * log2(e): sigmoid(x/K) = 1/(1+exp(-x*1000)) = 1/(1+exp2(-x*SCALE))
#define RS_SCALE 1442.6950408889634f
// bucket width == far-threshold 18 (sigmoid saturated to 0/1 within 2^-18)
#define W_INV (1.0f / 18.0f)
#define B_OFF 1530.0f
#define PADV -1600.0f   // pad sorts below all real rs (>= -1442.7), bucket 0
#define NB 172

static __device__ __forceinline__ float rcp_fast(float x) {
    return __builtin_amdgcn_rcpf(x);
}
static __device__ __forceinline__ float exp2_fast(float x) {
    return __builtin_amdgcn_exp2f(x);
}

// ---------------- K1: fused row-norms + scaled cosine-sim GEMM --------------
// 16x16 grid of 32x32 tiles (256 blocks = 1/CU), 256 threads, 2x2 microtile.
// Row norms computed during staging via 32-lane shfl reduce (deterministic).
__global__ __launch_bounds__(256) void map_sim_kernel(
    const float* __restrict__ x, float* __restrict__ rs,
    int* __restrict__ ticket)
{
    const int bi = blockIdx.x, bj = blockIdx.y, t = threadIdx.x;
    __shared__ float As[TS * D], Bs[TS * D];
    __shared__ float ssA[TS], ssB[TS];
    __shared__ float invA[TS], invB[TS];

    if (bi == 0 && bj == 0 && t == 0) *ticket = 0;  // reset fence counter

    const int lane = t & 63;
#pragma unroll
    for (int r = 0; r < 4; ++r) {
        int ch = t + 256 * r;            // [0,1024): 32 rows x 32 float4
        int row = ch >> 5, c4 = ch & 31; // 32 consecutive lanes share a row
        int sw = (c4 ^ (row >> 1)) << 2; // swizzle: frag reads spread banks
        float4 va = *(const float4*)(x + (bi * TS + row) * D + c4 * 4);
        *(float4*)(As + row * D + sw) = va;
        float pa = va.x * va.x + va.y * va.y + va.z * va.z + va.w * va.w;
        float4 vb = *(const float4*)(x + (bj * TS + row) * D + c4 * 4);
        *(float4*)(Bs + row * D + sw) = vb;
        float pb = vb.x * vb.x + vb.y * vb.y + vb.z * vb.z + vb.w * vb.w;
#pragma unroll
        for (int off = 16; off; off >>= 1) {  // reduce within 32-lane row group
            pa += __shfl_xor(pa, off);
            pb += __shfl_xor(pb, off);
        }
        if ((lane & 31) == 0) { ssA[row] = pa; ssB[row] = pb; }
    }
    __syncthreads();
    if (t < TS)          invA[t] = rcp_fast(fmaxf(sqrtf(ssA[t]), 1e-8f));
    else if (t < 2 * TS) invB[t - TS] = rcp_fast(fmaxf(sqrtf(ssB[t - TS]), 1e-8f));
    __syncthreads();

    const int tx = t & 15, ty = t >> 4;
    float acc00 = 0.f, acc01 = 0.f, acc10 = 0.f, acc11 = 0.f;
#pragma unroll 4
    for (int k4 = 0; k4 < D / 4; ++k4) {
        float4 a0 = *(const float4*)(As + (2 * ty) * D + ((k4 ^ ty) << 2));
        float4 a1 = *(const float4*)(As + (2 * ty + 1) * D + ((k4 ^ ty) << 2));
        float4 b0 = *(const float4*)(Bs + (2 * tx) * D + ((k4 ^ tx) << 2));
        float4 b1 = *(const float4*)(Bs + (2 * tx + 1) * D + ((k4 ^ tx) << 2));
        acc00 = fmaf(a0.x, b0.x, acc00); acc00 = fmaf(a0.y, b0.y, acc00);
        acc00 = fmaf(a0.z, b0.z, acc00); acc00 = fmaf(a0.w, b0.w, acc00);
        acc01 = fmaf(a0.x, b1.x, acc01); acc01 = fmaf(a0.y, b1.y, acc01);
        acc01 = fmaf(a0.z, b1.z, acc01); acc01 = fmaf(a0.w, b1.w, acc01);
        acc10 = fmaf(a1.x, b0.x, acc10); acc10 = fmaf(a1.y, b0.y, acc10);
        acc10 = fmaf(a1.z, b0.z, acc10); acc10 = fmaf(a1.w, b0.w, acc10);
        acc11 = fmaf(a1.x, b1.x, acc11); acc11 = fmaf(a1.y, b1.y, acc11);
        acc11 = fmaf(a1.z, b1.z, acc11); acc11 = fmaf(a1.w, b1.w, acc11);
    }

    const float sA0 = invA[2 * ty] * RS_SCALE;
    const float sA1 = invA[2 * ty + 1] * RS_SCALE;
    const float sB0 = invB[2 * tx], sB1 = invB[2 * tx + 1];
    const int gr = bi * TS + 2 * ty, gc = bj * TS + 2 * tx;
    *(float2*)(rs + gr * N + gc) =
        make_float2(acc00 * sA0 * sB0, acc01 * sA0 * sB1);
    *(float2*)(rs + (gr + 1) * N + gc) =
        make_float2(acc10 * sA1 * sB0, acc11 * sA1 * sB1);
}

// ---------------- K2: counting-sort + windowed AP + fused final -------------
__global__ __launch_bounds__(512) void map_ap_kernel(
    const float* __restrict__ rs, const int* __restrict__ tgt,
    float2* __restrict__ av, int* __restrict__ ticket,
    float* __restrict__ out)
{
    const int i = blockIdx.x, t = threadIdx.x;
    __shared__ int hist[256];   // packed (count<<10)|gtcount -> inclusive scan
    __shared__ int offs[NB];
    __shared__ int wtot[4];
    __shared__ float2 skv[N];   // bucket-sorted {key, gt}
    __shared__ float red[16];
    __shared__ int amLast;

    if (t < 256) hist[t] = 0;
    if (t < NB) offs[t] = 0;
    const int ti = tgt[i];
    const bool self = (t == i);
    const float val = self ? PADV : rs[i * N + t];
    const int gti = (!self && tgt[t] == ti) ? 1 : 0;
    int q = (int)((val + B_OFF) * W_INV);
    q = max(0, min(NB - 1, q));
    __syncthreads();
    atomicAdd(&hist[q], (1 << 10) | gti);
    __syncthreads();

    // wave-level inclusive scan of hist[0..255] (packed fields scan together)
    int v = (t < 256) ? hist[t] : 0;
    const int lane = t & 63;
#pragma unroll
    for (int off = 1; off < 64; off <<= 1) {
        int u = __shfl_up(v, off);
        if (lane >= off) v += u;
    }
    if (t < 256 && lane == 63) wtot[t >> 6] = v;
    __syncthreads();
    if (t < 256) {
        int w = t >> 6, add = 0;
        if (w > 0) add += wtot[0];
        if (w > 1) add += wtot[1];
        if (w > 2) add += wtot[2];
        hist[t] = v + add;
    }
    __syncthreads();

    // scatter into bucket-sorted order
    {
        int base = (q > 0) ? (hist[q - 1] >> 10) : 0;
        int pos = base + atomicAdd(&offs[q], 1);
        skv[pos] = make_float2(val, (float)gti);
    }
    __syncthreads();

    // j = sorted position t; window = buckets [qj-1, qj+1]
    const float2 me = skv[t];
    const float rj = me.x, gtj = me.y;
    int qj = (int)((rj + B_OFF) * W_INV);
    qj = max(0, min(NB - 1, qj));
    const int lo = (qj > 1) ? (hist[qj - 2] >> 10) : 0;
    const int e1 = min(qj + 1, NB - 1);
    const int hi = hist[e1] >> 10;

    float dsum = (float)(N - hi);  // buckets >= qj+2: sigmoid == 1
    float gsum = (float)((hist[NB - 1] & 1023) - (hist[e1] & 1023));
    for (int idx = lo; idx < hi; ++idx) {
        float2 kv = skv[idx];
        // sigmoid((r_l - r_j)/K) = 1/(1+exp2(rs_j - rs_l)); idx==t gives 0.5
        float s = rcp_fast(1.f + exp2_fast(rj - kv.x));
        dsum += s;
        gsum = fmaf(kv.y, s, gsum);
    }

    float prec = gsum * rcp_fast(dsum + 0.5f);
    float ap = gtj * prec;  // pad thread: gtj = 0
    float np = gtj;

#pragma unroll
    for (int off = 32; off; off >>= 1) {
        ap += __shfl_down(ap, off);
        np += __shfl_down(np, off);
    }
    if ((t & 63) == 0) { red[(t >> 6) * 2] = ap; red[(t >> 6) * 2 + 1] = np; }
    __syncthreads();
    if (t == 0) {
        float A = 0.f, P = 0.f;
#pragma unroll
        for (int k = 0; k < 8; ++k) { A += red[2 * k]; P += red[2 * k + 1]; }
        av[i] = make_float2((P > 0.f) ? (A * rcp_fast(P)) : 0.f,
                            (P > 0.f) ? 1.f : 0.f);
        __threadfence();                       // release av[i]
        int old = atomicAdd(ticket, 1);
        amLast = (old == (int)gridDim.x - 1) ? 1 : 0;
    }
    __syncthreads();

    if (amLast) {  // block-uniform: last block reduces av[] and writes out
        __threadfence();                       // acquire
        float2 p = av[t];
        float a = p.x, vv = p.y;
#pragma unroll
        for (int off = 32; off; off >>= 1) {
            a += __shfl_down(a, off);
            vv += __shfl_down(vv, off);
        }
        if ((t & 63) == 0) { red[(t >> 6) * 2] = a; red[(t >> 6) * 2 + 1] = vv; }
        __syncthreads();
        if (t == 0) {
            float A = 0.f, V = 0.f;
#pragma unroll
            for (int k = 0; k < 8; ++k) { A += red[2 * k]; V += red[2 * k + 1]; }
            out[0] = 1.0f - A * rcp_fast(V);
        }
    }
}

extern "C" void kernel_launch(void* const* d_in, const int* in_sizes, int n_in,
                              void* d_out, int out_size, void* d_ws, size_t ws_size,
                              hipStream_t stream) {
    const float* x = (const float*)d_in[0];
    const int* tgt = (const int*)d_in[1];
    float* out = (float*)d_out;

    float* rs = (float*)d_ws;                                 // 1 MB
    float2* av = (float2*)((char*)d_ws + N * N * 4);          // 4 KB
    int* ticket = (int*)((char*)d_ws + N * N * 4 + N * 8);    // 4 B

    map_sim_kernel<<<dim3(N / TS, N / TS), 256, 0, stream>>>(x, rs, ticket);
    map_ap_kernel<<<N, 512, 0, stream>>>(rs, tgt, av, ticket, out);
}